// Round 1
// baseline (553.302 us; speedup 1.0000x reference)
//
#include <hip/hip_runtime.h>
#include <math.h>

#define C 100
#define NBINS 15

// Pass 1: each 32-lane group handles one row of 100 fp32 logits.
// Row byte offset = row*400, which is 16B-aligned -> float4 loads, lanes 0..24.
__global__ __launch_bounds__(256) void ece_pass1(
    const float* __restrict__ probs, const int* __restrict__ labels,
    float* __restrict__ partials, int N, int G) {
  __shared__ float sbin[2 * NBINS];  // [0..14]=sum conf, [15..29]=sum correct
  if (threadIdx.x < 2 * NBINS) sbin[threadIdx.x] = 0.0f;
  __syncthreads();

  const int lane  = threadIdx.x & 31;
  const int group = threadIdx.x >> 5;
  const int gpb   = blockDim.x >> 5;   // 8 groups per block
  const int stride = G * gpb;

  for (int row = blockIdx.x * gpb + group; row < N; row += stride) {
    const float4* rp = (const float4*)(probs + (size_t)row * C);
    float4 v;
    if (lane < 25) v = rp[lane];
    else           v = make_float4(-INFINITY, -INFINITY, -INFINITY, -INFINITY);

    // local max + argmax (first occurrence wins on ties)
    float mv = v.x; int mi = 4 * lane;
    if (v.y > mv) { mv = v.y; mi = 4 * lane + 1; }
    if (v.z > mv) { mv = v.z; mi = 4 * lane + 2; }
    if (v.w > mv) { mv = v.w; mi = 4 * lane + 3; }
    if (lane >= 25) mi = 0x7fffffff;

    // 32-lane butterfly (xor masks <=16 stay within each 32-lane half of the wave)
    #pragma unroll
    for (int m = 16; m >= 1; m >>= 1) {
      float ov = __shfl_xor(mv, m);
      int   oi = __shfl_xor(mi, m);
      if (ov > mv || (ov == mv && oi < mi)) { mv = ov; mi = oi; }
    }

    float se = 0.0f;
    if (lane < 25)
      se = __expf(v.x - mv) + __expf(v.y - mv) + __expf(v.z - mv) + __expf(v.w - mv);
    #pragma unroll
    for (int m = 16; m >= 1; m >>= 1) se += __shfl_xor(se, m);

    if (lane == 0) {
      float conf = 1.0f / se;                         // exp(max)/sum exp = 1/sum exp(x-max)
      float corr = (labels[row] == mi) ? 1.0f : 0.0f;
      // bin = clip(searchsorted(linspace(0,1,16), conf, 'left') - 1, 0, 14)
      //     = clip(count(boundaries < conf) - 1, 0, 14)
      int cnt = 0;
      #pragma unroll
      for (int i = 0; i <= NBINS; ++i)
        cnt += (((float)i / (float)NBINS) < conf) ? 1 : 0;
      int bin = cnt - 1;
      bin = bin < 0 ? 0 : (bin > NBINS - 1 ? NBINS - 1 : bin);
      atomicAdd(&sbin[bin], conf);
      atomicAdd(&sbin[NBINS + bin], corr);
    }
  }

  __syncthreads();
  // column-major partials: partials[col*G + block], col in [0,30)
  if (threadIdx.x < 2 * NBINS)
    partials[(size_t)threadIdx.x * G + blockIdx.x] = sbin[threadIdx.x];
}

// Pass 2: single block; 32-lane group g reduces column g over G blocks (double),
// then thread 0 computes sum_b |sum_conf_b - sum_corr_b| / N.
__global__ __launch_bounds__(1024) void ece_pass2(
    const float* __restrict__ partials, float* __restrict__ out, int G, int N) {
  __shared__ double cols[32];
  const int lane = threadIdx.x & 31;
  const int grp  = threadIdx.x >> 5;   // 32 groups; 30 used
  double s = 0.0;
  if (grp < 2 * NBINS) {
    for (int g = lane; g < G; g += 32)
      s += (double)partials[(size_t)grp * G + g];
  }
  #pragma unroll
  for (int m = 16; m >= 1; m >>= 1) s += __shfl_xor(s, m);
  if (lane == 0) cols[grp] = s;
  __syncthreads();
  if (threadIdx.x == 0) {
    double e = 0.0;
    for (int b = 0; b < NBINS; ++b) e += fabs(cols[b] - cols[NBINS + b]);
    out[0] = (float)(e / (double)N);
  }
}

extern "C" void kernel_launch(void* const* d_in, const int* in_sizes, int n_in,
                              void* d_out, int out_size, void* d_ws, size_t ws_size,
                              hipStream_t stream) {
  const float* probs  = (const float*)d_in[0];
  const int*   labels = (const int*)d_in[1];
  float*       out    = (float*)d_out;
  float*       partials = (float*)d_ws;

  const int N = in_sizes[1];            // number of rows (labels count)

  int G = 2048;                         // 2048 blocks * 4 waves = 32 waves/CU
  size_t need = (size_t)2 * NBINS * G * sizeof(float);
  if (ws_size < need) {
    G = (int)(ws_size / ((size_t)2 * NBINS * sizeof(float)));
    if (G < 1) G = 1;
  }

  ece_pass1<<<G, 256, 0, stream>>>(probs, labels, partials, N, G);
  ece_pass2<<<1, 1024, 0, stream>>>(partials, out, G, N);
}